// Round 3
// baseline (381.398 us; speedup 1.0000x reference)
//
#include <hip/hip_runtime.h>
#include <hip/hip_bf16.h>

typedef __attribute__((ext_vector_type(8))) short bf16x8;
typedef __attribute__((ext_vector_type(4))) float f32x4;

#define BB   64
#define LL   512
#define CIN  64
#define FF   128
#define KW   7
#define OUTL 506
#define LPAD 518        // 512 + 3 + 3
#define KC   448        // KW*CIN  (conv GEMM K)
#define KL   896        // KW*FF   (local GEMM K)
#define BK2  64         // local GEMM K-chunk staged in LDS
#define NCH2 14         // KL / BK2
#define EPSV 1e-3f

#define NPAD  (BB * LPAD * CIN)      // 2,121,728
#define PADB  (NPAD / 256)           // 8288 (exact)
#define NWT   (FF * KC)              // 57,344
#define WTB   (NWT / 256)            // 224 (exact)

static __device__ __forceinline__ short f2bf(float f) {
    // fp32 -> bf16, round-to-nearest-even
    unsigned u = __builtin_bit_cast(unsigned, f);
    unsigned r = (u + 0x7fffu + ((u >> 16) & 1u)) >> 16;
    return (short)r;
}

// async global->LDS, 16 B per lane; LDS dest = wave-uniform base + lane*16
static __device__ __forceinline__ void g2lds16(const float* g, float* l) {
    __builtin_amdgcn_global_load_lds(
        (const __attribute__((address_space(1))) unsigned int*)g,
        (__attribute__((address_space(3))) unsigned int*)l, 16, 0, 0);
}

// ---------------------------------------------------------------- kernel 0
// blocks [0, PADB): zero-pad x by 3 each side of L, cast bf16 -> xp (B,518,64)
// blocks [PADB, PADB+WTB): transpose+cast conv_w (448,128) -> wt[n][k] bf16
__global__ void prep_kernel(const float* __restrict__ x, const float* __restrict__ w,
                            short* __restrict__ xp, short* __restrict__ wt) {
    if (blockIdx.x < PADB) {
        int i = blockIdx.x * 256 + threadIdx.x;
        int c  = i & (CIN - 1);
        int t  = i >> 6;            // b*LPAD + lp
        int lp = t % LPAD;
        int b  = t / LPAD;
        float v = 0.0f;
        int l = lp - 3;
        if (l >= 0 && l < LL) v = x[(b * LL + l) * CIN + c];
        xp[i] = f2bf(v);
    } else {
        int i = (blockIdx.x - PADB) * 256 + threadIdx.x;  // < 57344
        int n = i / KC;
        int k = i - n * KC;
        wt[i] = f2bf(w[(size_t)k * FF + n]);
    }
}

// ---------------------------------------------------------------- kernel 1
// conv-as-GEMM: M = B*L, K = 448, N = 128.  A = xp rows (contiguous bf16),
// B = wt[n][k] (contiguous bf16x8 per frag, L2-resident). BN1+ReLU -> y bf16.
__global__ __launch_bounds__(256) void conv_bn_kernel(
    const short* __restrict__ xp, const short* __restrict__ wt,
    const float* __restrict__ cb, const float* __restrict__ g,
    const float* __restrict__ be, const float* __restrict__ mu,
    const float* __restrict__ va, short* __restrict__ y) {
    const int lane = threadIdx.x & 63;
    const int wid  = threadIdx.x >> 6;
    const int m0   = blockIdx.x * 64;
    const int nb   = wid * 32;
    const int q    = lane >> 4;
    const int ln   = lane & 15;

    const short* arow[4];
#pragma unroll
    for (int mt = 0; mt < 4; ++mt) {
        int m = m0 + mt * 16 + ln;
        int b = m >> 9, l = m & 511;           // m = b*512 + l
        arow[mt] = xp + (b * LPAD + l) * CIN;  // 448 contiguous bf16 (padded)
    }
    const short* brow[2];
#pragma unroll
    for (int nt = 0; nt < 2; ++nt)
        brow[nt] = wt + (size_t)(nb + nt * 16 + ln) * KC;

    f32x4 acc[4][2];
#pragma unroll
    for (int mt = 0; mt < 4; ++mt)
#pragma unroll
        for (int nt = 0; nt < 2; ++nt) acc[mt][nt] = (f32x4){0.f, 0.f, 0.f, 0.f};

#pragma unroll 2
    for (int kc = 0; kc < KC; kc += 32) {
        const int ko = kc + q * 8;
        bf16x8 a[4], bf[2];
#pragma unroll
        for (int mt = 0; mt < 4; ++mt) a[mt] = *(const bf16x8*)(arow[mt] + ko);
#pragma unroll
        for (int nt = 0; nt < 2; ++nt) bf[nt] = *(const bf16x8*)(brow[nt] + ko);
#pragma unroll
        for (int mt = 0; mt < 4; ++mt)
#pragma unroll
            for (int nt = 0; nt < 2; ++nt)
                acc[mt][nt] = __builtin_amdgcn_mfma_f32_16x16x32_bf16(
                    a[mt], bf[nt], acc[mt][nt], 0, 0, 0);
    }

#pragma unroll
    for (int nt = 0; nt < 2; ++nt) {
        const int n = nb + nt * 16 + ln;
        const float s  = g[n] * rsqrtf(va[n] + EPSV);
        const float b2 = s * (cb[n] - mu[n]) + be[n];
#pragma unroll
        for (int mt = 0; mt < 4; ++mt) {
            const int mbase = m0 + mt * 16 + q * 4;
#pragma unroll
            for (int r = 0; r < 4; ++r) {
                float v = fmaxf(acc[mt][nt][r] * s + b2, 0.0f);
                y[(size_t)(mbase + r) * FF + n] = f2bf(v);
            }
        }
    }
}

// ---------------------------------------------------------------- kernel 2
// locally-connected, N-split: one block per (l, col-half). grid = 1012 -> ~4
// blocks/CU. C(64 x 64) = A(64 x 896) @ W_l[:, nh*64 : nh*64+64].
// Weights: disjoint 224 KB stream per block, BK2=64 fp32 chunks (16 KB)
// double-buffered via global_load_lds. Waves own 16-col tiles (B-frag reads
// cheap); A-frags are direct global bf16x8 loads from y.
__global__ __launch_bounds__(256) void local_bn_kernel(
    const short* __restrict__ y, const float* __restrict__ lw,
    const float* __restrict__ lb, const float* __restrict__ g,
    const float* __restrict__ be, const float* __restrict__ mu,
    const float* __restrict__ va, float* __restrict__ out) {
    __shared__ float wtile[2][BK2 * 64];       // 2 x 16 KB
    const int bx   = blockIdx.x;
    const int l    = bx >> 1;
    const int nh   = bx & 1;
    const int lane = threadIdx.x & 63;
    const int wid  = threadIdx.x >> 6;
    const int q    = lane >> 4;                // also row-in-inst for staging
    const int ln   = lane & 15;
    const int nloc = wid * 16 + ln;            // col within block, 0..63

    // weight slice base: rows k, cols [nh*64, nh*64+64)
    const float* wl = lw + (size_t)l * (KL * FF) + nh * 64;

    const short* arow[4];
#pragma unroll
    for (int mt = 0; mt < 4; ++mt)
        arow[mt] = y + (size_t)(mt * 16 + ln) * (LL * FF) + (size_t)l * FF;

    f32x4 acc[4];
#pragma unroll
    for (int mt = 0; mt < 4; ++mt) acc[mt] = (f32x4){0.f, 0.f, 0.f, 0.f};

    // stage chunk c (64 rows x 64 cols fp32) into wtile[buf]:
    // wave wid loads rows [wid*16, wid*16+16): 4 insts x (4 rows x 256 B).
    // LDS layout: [k_in_chunk][64 cols] linear -> matches lane order exactly.
#define STAGE(c, buf)                                                          \
    {                                                                          \
        _Pragma("unroll")                                                      \
        for (int i = 0; i < 4; ++i) {                                          \
            const float* src =                                                 \
                wl + (size_t)((c) * BK2 + wid * 16 + i * 4 + q) * FF + ln * 4; \
            g2lds16(src, &wtile[buf][wid * 1024 + i * 256]);                   \
        }                                                                      \
    }

    STAGE(0, 0)

    for (int c = 0; c < NCH2; ++c) {
        __syncthreads();                       // chunk c resident; buf free
        if (c + 1 < NCH2) STAGE(c + 1, (c + 1) & 1)
        const float* wb = wtile[c & 1];

#pragma unroll
        for (int s = 0; s < 2; ++s) {          // two K=32 MFMA steps
            const int ko = c * BK2 + s * 32 + q * 8;
            bf16x8 a[4];
#pragma unroll
            for (int mt = 0; mt < 4; ++mt)
                a[mt] = *(const bf16x8*)(arow[mt] + ko);
            bf16x8 bf;
#pragma unroll
            for (int j = 0; j < 8; ++j)
                bf[j] = f2bf(wb[(s * 32 + q * 8 + j) * 64 + nloc]);
#pragma unroll
            for (int mt = 0; mt < 4; ++mt)
                acc[mt] = __builtin_amdgcn_mfma_f32_16x16x32_bf16(
                    a[mt], bf, acc[mt], 0, 0, 0);
        }
    }

    // epilogue: + local_b[l], BN2, ReLU, fp32 store
    const int n = nh * 64 + nloc;
    const float sc = g[n] * rsqrtf(va[n] + EPSV);
    const float b2 = sc * (lb[(size_t)l * FF + n] - mu[n]) + be[n];
#pragma unroll
    for (int mt = 0; mt < 4; ++mt) {
        const int bbase = mt * 16 + q * 4;
#pragma unroll
        for (int r = 0; r < 4; ++r) {
            float v = fmaxf(acc[mt][r] * sc + b2, 0.0f);
            out[(size_t)(bbase + r) * (OUTL * FF) + (size_t)l * FF + n] = v;
        }
    }
#undef STAGE
}

// ---------------------------------------------------------------- launch
extern "C" void kernel_launch(void* const* d_in, const int* in_sizes, int n_in,
                              void* d_out, int out_size, void* d_ws, size_t ws_size,
                              hipStream_t stream) {
    const float* x       = (const float*)d_in[0];
    const float* conv_w  = (const float*)d_in[1];
    const float* conv_b  = (const float*)d_in[2];
    const float* bn1_g   = (const float*)d_in[3];
    const float* bn1_b   = (const float*)d_in[4];
    const float* bn1_m   = (const float*)d_in[5];
    const float* bn1_v   = (const float*)d_in[6];
    const float* local_w = (const float*)d_in[7];
    const float* local_b = (const float*)d_in[8];
    const float* bn2_g   = (const float*)d_in[9];
    const float* bn2_b   = (const float*)d_in[10];
    const float* bn2_m   = (const float*)d_in[11];
    const float* bn2_v   = (const float*)d_in[12];
    float* out = (float*)d_out;

    short* xp  = (short*)d_ws;                   // (64, 518, 64) bf16
    short* ybf = xp + (size_t)NPAD;              // (64, 512, 128) bf16
    short* wt  = ybf + (size_t)BB * LL * FF;     // (128, 448) bf16

    prep_kernel<<<PADB + WTB, 256, 0, stream>>>(x, conv_w, xp, wt);
    conv_bn_kernel<<<(BB * LL) / 64, 256, 0, stream>>>(
        xp, wt, conv_b, bn1_g, bn1_b, bn1_m, bn1_v, ybf);
    local_bn_kernel<<<OUTL * 2, 256, 0, stream>>>(
        ybf, local_w, local_b, bn2_g, bn2_b, bn2_m, bn2_v, out);
}